// Round 2
// baseline (636.108 us; speedup 1.0000x reference)
//
#include <hip/hip_runtime.h>
#include <hip/hip_bf16.h>

// LoRA linear: out = x @ (W.T + (alpha/rank) * B@A) + bias
// x: [65536, 1024] f32, W: [1024,1024] f32 ([out,in]), bias: [1024] f32,
// B: [1024,16] f32, A: [16,1024] f32. out: [65536,1024] f32.
// Strategy: build WeffT[n][k] = W[n][k] + 2*(B@A)[k][n] in bf16 (d_ws),
// then bf16 MFMA GEMM (16x16x32), fused f32->bf16 conversion of x in staging.

typedef short short8 __attribute__((ext_vector_type(8)));   // 8 bf16 = 4 VGPRs
typedef float f32x4 __attribute__((ext_vector_type(4)));

#define K_DIM 1024
#define N_DIM 1024
#define BM 128
#define BN 128
#define BK 64
#define XS_STRIDE 72   // shorts; +8 pad keeps ds_read_b128 bank-uniform

static __device__ __forceinline__ unsigned short f2bf_rne(float v) {
    unsigned u = __builtin_bit_cast(unsigned, v);
    u += 0x7fffu + ((u >> 16) & 1u);
    return (unsigned short)(u >> 16);
}

// ---------------- Kernel 1: effective weight (transposed, bf16) ----------------
// WeffT[n*1024 + k] = bf16( W[n*1024+k] + 2 * sum_r B[k*16+r] * A[r*1024+n] )
__global__ __launch_bounds__(256) void weff_kernel(
    const float* __restrict__ W, const float* __restrict__ B,
    const float* __restrict__ A, unsigned short* __restrict__ WeffT) {
    int idx = blockIdx.x * 256 + threadIdx.x;   // n*1024 + k
    int n = idx >> 10;
    int k = idx & 1023;
    const float4* Bk = (const float4*)(B + k * 16);
    float s = 0.f;
#pragma unroll
    for (int r4 = 0; r4 < 4; ++r4) {
        float4 b4 = Bk[r4];
        s += b4.x * A[(r4 * 4 + 0) * N_DIM + n];
        s += b4.y * A[(r4 * 4 + 1) * N_DIM + n];
        s += b4.z * A[(r4 * 4 + 2) * N_DIM + n];
        s += b4.w * A[(r4 * 4 + 3) * N_DIM + n];
    }
    float v = W[idx] + 2.0f * s;
    WeffT[idx] = f2bf_rne(v);
}

// ---------------- Kernel 2: GEMM C = X @ WeffT^T + bias ----------------
__global__ __launch_bounds__(256) void lora_gemm(
    const float* __restrict__ X, const unsigned short* __restrict__ WeffT,
    const float* __restrict__ bias, float* __restrict__ Out) {
    __shared__ short Xs[BM * XS_STRIDE];  // 18432 B, padded, VGPR-staged
    __shared__ short Ws[BN * BK];         // 16384 B, unpadded (lds-DMA), XOR-swizzled

    const int t = threadIdx.x;
    const int lane = t & 63;
    const int w = t >> 6;        // wave 0..3
    const int quad = lane >> 4;  // 0..3
    const int l15 = lane & 15;

    // XCD swizzle: 8 consecutive slots on one XCD = the 8 N-tiles of one M-tile
    // (bid % 8 round-robins XCDs), so each X-tile is HBM-fetched once per XCD.
    const int bid = blockIdx.x;
    const int xcd = bid & 7;
    const int s = bid >> 3;
    const int m_tile = (s >> 3) * 8 + xcd;  // 0..511
    const int n_tile = s & 7;               // 0..7
    const int m_base = m_tile * BM;
    const int n_base = n_tile * BN;

    f32x4 acc[4][4];
#pragma unroll
    for (int mi = 0; mi < 4; ++mi)
#pragma unroll
        for (int ni = 0; ni < 4; ++ni)
            acc[mi][ni] = (f32x4){0.f, 0.f, 0.f, 0.f};

    for (int k0 = 0; k0 < K_DIM; k0 += BK) {
        // --- stage WeffT tile via async lds-DMA (16B/lane), XOR chunk swizzle ---
        // 128 rows x 8 chunks of 16B = 1024 slots -> 4 iterations x 256 threads
#pragma unroll
        for (int i = 0; i < 4; ++i) {
            int li = i * 256 + t;           // 0..1023 slots of 8 shorts
            int row = li >> 3;              // n within tile, 0..127
            int c = li & 7;                 // lds chunk
            int gc = c ^ (row & 7);         // global chunk actually stored here
            const unsigned short* gp =
                WeffT + (size_t)(n_base + row) * K_DIM + k0 + gc * 8;
            __builtin_amdgcn_global_load_lds(
                (const __attribute__((address_space(1))) unsigned int*)gp,
                (__attribute__((address_space(3))) unsigned int*)&Ws[(i * 256 + w * 64) * 8],
                16, 0, 0);
        }
        // --- stage X tile: f32 load -> bf16 RNE -> padded LDS ---
#pragma unroll
        for (int it = 0; it < 4; ++it) {
            int g = it * 256 + t;           // 0..1023 chunks of 8 floats
            int row = g >> 3;               // m within tile
            int c = g & 7;                  // 8-float chunk
            const float4* gp = (const float4*)(X + (size_t)(m_base + row) * K_DIM + k0 + c * 8);
            float4 v0 = gp[0];
            float4 v1 = gp[1];
            short8 p;
            p[0] = (short)f2bf_rne(v0.x); p[1] = (short)f2bf_rne(v0.y);
            p[2] = (short)f2bf_rne(v0.z); p[3] = (short)f2bf_rne(v0.w);
            p[4] = (short)f2bf_rne(v1.x); p[5] = (short)f2bf_rne(v1.y);
            p[6] = (short)f2bf_rne(v1.z); p[7] = (short)f2bf_rne(v1.w);
            *(short8*)(&Xs[row * XS_STRIDE + c * 8]) = p;
        }
        __syncthreads();  // drains vmcnt (lds-DMA) + lgkmcnt

        // --- 2 k-chunks of 32, 4x4 MFMAs each; wave w owns 64x64 quadrant ---
#pragma unroll
        for (int kc = 0; kc < 2; ++kc) {
            short8 a[4], b[4];
#pragma unroll
            for (int mi = 0; mi < 4; ++mi) {
                int row = (w >> 1) * 64 + mi * 16 + l15;
                a[mi] = *(const short8*)(&Xs[row * XS_STRIDE + kc * 32 + quad * 8]);
            }
#pragma unroll
            for (int ni = 0; ni < 4; ++ni) {
                int row = (w & 1) * 64 + ni * 16 + l15;
                int c = (kc * 4 + quad) ^ (row & 7);
                b[ni] = *(const short8*)(&Ws[row * BK + c * 8]);
            }
#pragma unroll
            for (int mi = 0; mi < 4; ++mi)
#pragma unroll
                for (int ni = 0; ni < 4; ++ni)
                    acc[mi][ni] = __builtin_amdgcn_mfma_f32_16x16x32_bf16(
                        a[mi], b[ni], acc[mi][ni], 0, 0, 0);
        }
        __syncthreads();  // protect LDS before next iteration's writes
    }

    // --- epilogue: C/D layout col=lane&15, row=quad*4+reg ---
#pragma unroll
    for (int ni = 0; ni < 4; ++ni) {
        int col = n_base + (w & 1) * 64 + ni * 16 + l15;
        float bv = bias[col];
#pragma unroll
        for (int mi = 0; mi < 4; ++mi) {
            int row0 = m_base + (w >> 1) * 64 + mi * 16 + quad * 4;
#pragma unroll
            for (int r = 0; r < 4; ++r) {
                Out[(size_t)(row0 + r) * N_DIM + col] = acc[mi][ni][r] + bv;
            }
        }
    }
}

extern "C" void kernel_launch(void* const* d_in, const int* in_sizes, int n_in,
                              void* d_out, int out_size, void* d_ws, size_t ws_size,
                              hipStream_t stream) {
    const float* x    = (const float*)d_in[0];
    const float* W    = (const float*)d_in[1];
    const float* bias = (const float*)d_in[2];
    const float* B    = (const float*)d_in[3];
    const float* A    = (const float*)d_in[4];
    float* out = (float*)d_out;
    unsigned short* WeffT = (unsigned short*)d_ws;  // 1024*1024 bf16 = 2 MB

    // Kernel 1: 1M elements / 256 = 4096 blocks
    weff_kernel<<<4096, 256, 0, stream>>>(W, B, A, WeffT);

    // Kernel 2: M = out_size / N
    int M = out_size / N_DIM;            // 65536
    int grid = (M / BM) * (N_DIM / BN);  // 512 * 8 = 4096
    lora_gemm<<<grid, 256, 0, stream>>>(x, WeffT, bias, out);
}